// Round 6
// baseline (422.929 us; speedup 1.0000x reference)
//
#include <hip/hip_runtime.h>
#include <stdint.h>

#define NH 16
#define SEQ 2048
#define HDIM 1024

typedef short bf16x8 __attribute__((ext_vector_type(8)));
typedef float f32x4 __attribute__((ext_vector_type(4)));

#define NEG_BIG (-200.0f)   // exp2(-200) == 0

#if defined(__HIP_DEVICE_COMPILE__) && __has_builtin(__builtin_amdgcn_exp2f)
#define EXP2F(x) __builtin_amdgcn_exp2f(x)
#else
#define EXP2F(x) exp2f(x)
#endif

#define MFMA32(A, B, C) __builtin_amdgcn_mfma_f32_16x16x32_bf16(A, B, C, 0, 0, 0)

static __device__ __forceinline__ uint16_t f2bf(float f) {  // RNE
  uint32_t u = __builtin_bit_cast(uint32_t, f);
  return (uint16_t)((u + 0x7FFFu + ((u >> 16) & 1u)) >> 16);
}
static __device__ __forceinline__ uint32_t pack2bf_rne(float a, float b) {
  return (uint32_t)f2bf(a) | ((uint32_t)f2bf(b) << 16);
}
// truncating 2xfp32 -> packed bf16 (for P; rel err 2^-9, fine vs 2% tol)
static __device__ __forceinline__ uint32_t pack2bf_trunc(float a, float b) {
  return (__builtin_bit_cast(uint32_t, a) >> 16) |
         (__builtin_bit_cast(uint32_t, b) & 0xffff0000u);
}
static __device__ __forceinline__ float bf2f(uint32_t u) {
  union { uint32_t u; float f; } v; v.u = u << 16; return v.f;
}
static __device__ __forceinline__ void gload16(const void* g, void* l) {
  __builtin_amdgcn_global_load_lds((const __attribute__((address_space(1))) void*)g,
                                   (__attribute__((address_space(3))) void*)l, 16, 0, 0);
}

// ---- f32 -> bf16 bulk convert: exact grid, 8192 blocks ----
struct CvtArgs {
  const float* src[7];
  uint16_t* dst[7];
};
__global__ __launch_bounds__(256) void cvt_bf16(CvtArgs a) {
  int x = blockIdx.x;
  int ten, blk;
  if (x < 6144) { ten = x >> 11; blk = x & 2047; }               // q/k/v
  else { int y = x - 6144; ten = 3 + (y >> 9); blk = y & 511; }  // weights
  size_t idx = ((size_t)blk * 256 + threadIdx.x) * 8;
  const float* s = a.src[ten] + idx;
  float4 f0 = *(const float4*)(s);
  float4 f1 = *(const float4*)(s + 4);
  uint4 o;
  o.x = pack2bf_rne(f0.x, f0.y);
  o.y = pack2bf_rne(f0.z, f0.w);
  o.z = pack2bf_rne(f1.x, f1.y);
  o.w = pack2bf_rne(f1.z, f1.w);
  *(uint4*)(a.dst[ten] + idx) = o;
}

// cm[b,q,k] = mask ? sm * (log2e/8) : -1.0 (bf16); sm f32, mask int32
__global__ __launch_bounds__(256) void cm_prep(const int4* __restrict__ mask,
                                               const float4* __restrict__ sm,
                                               uint4* __restrict__ cm) {
  int i = blockIdx.x * 256 + threadIdx.x;
  int4 m0 = mask[2 * i];
  int4 m1 = mask[2 * i + 1];
  float4 s0 = sm[2 * i];
  float4 s1 = sm[2 * i + 1];
  const float c = 0.18033688011112042f;  // log2(e)/8
  auto pk = [&](int mA, int mB, float fa, float fb) -> uint32_t {
    uint32_t o0 = mA ? (uint32_t)f2bf(fa * c) : 0xBF80u;
    uint32_t o1 = mB ? (uint32_t)f2bf(fb * c) : 0xBF80u;
    return o0 | (o1 << 16);
  };
  uint4 o;
  o.x = pk(m0.x, m0.y, s0.x, s0.y);
  o.y = pk(m0.z, m0.w, s0.z, s0.w);
  o.z = pk(m1.x, m1.y, s1.x, s1.y);
  o.w = pk(m1.z, m1.w, s1.z, s1.w);
  cm[i] = o;
}

struct GemmArgs {
  const uint16_t* A[4];
  const uint16_t* B[4];
  const float* bias[4];
  void* C[4];
};

// m97-style: 128x128 tile, BK=32, global_load_lds width-16 staging.
// mode 0: Q -> [b,h,s,hd] bf16; 1: K same; 2: Wv@value^T -> vt [b,h,hd,s];
// 3: out -> f32 row-major.
__global__ __launch_bounds__(256) void gemm_bt(GemmArgs ga, int modeBase) {
  int mode = modeBase + blockIdx.y;
  const uint16_t* __restrict__ A = ga.A[mode];
  const uint16_t* __restrict__ Bm = ga.B[mode];
  const float* __restrict__ bias = ga.bias[mode];

  int bid = blockIdx.x;
  int tm, tn;
  if (mode == 2) { tm = bid & 7; tn = bid >> 3; }
  else           { tm = bid >> 3; tn = bid & 7; }

  __shared__ uint16_t As[128 * 32];
  __shared__ uint16_t Bs[128 * 32];

  int t = threadIdx.x;
  int lane = t & 63, w = t >> 6;
  int quad = lane >> 4, lm = lane & 15;
  int wm = w >> 1, wn = w & 1;

  const uint16_t* Ab = A + (size_t)tm * 128 * 1024;
  const uint16_t* Bb = Bm + (size_t)tn * 128 * 1024;
  int srow = w * 32 + (lane >> 2);
  int scol = (lane & 3) * 8;
  uint16_t* AsW = As + w * 1024;   // wave-uniform base; HW adds lane*16B
  uint16_t* BsW = Bs + w * 1024;

  f32x4 acc[4][4] = {};

  for (int kk = 0; kk < 1024; kk += 32) {
    __syncthreads();
    gload16(Ab + (size_t)srow * 1024 + kk + scol, AsW);
    gload16(Ab + (size_t)(srow + 16) * 1024 + kk + scol, AsW + 512);
    gload16(Bb + (size_t)srow * 1024 + kk + scol, BsW);
    gload16(Bb + (size_t)(srow + 16) * 1024 + kk + scol, BsW + 512);
    __syncthreads();
    bf16x8 af[4], bfr[4];
#pragma unroll
    for (int i = 0; i < 4; i++)
      af[i] = *(const bf16x8*)&As[(wm * 64 + i * 16 + lm) * 32 + quad * 8];
#pragma unroll
    for (int j = 0; j < 4; j++)
      bfr[j] = *(const bf16x8*)&Bs[(wn * 64 + j * 16 + lm) * 32 + quad * 8];
#pragma unroll
    for (int i = 0; i < 4; i++)
#pragma unroll
      for (int j = 0; j < 4; j++)
        acc[i][j] = MFMA32(af[i], bfr[j], acc[i][j]);
  }

  int rowb = tm * 128 + wm * 64;
  int colb = tn * 128 + wn * 64;
#pragma unroll
  for (int i = 0; i < 4; i++) {
#pragma unroll
    for (int j = 0; j < 4; j++) {
      int col = colb + j * 16 + lm;
#pragma unroll
      for (int r = 0; r < 4; r++) {
        int row = rowb + i * 16 + quad * 4 + r;
        float v = acc[i][j][r];
        if (mode == 2) {
          v += bias[row];
          int hh = row >> 6, hd = row & 63, b = col >> 11, s2 = col & 2047;
          ((uint16_t*)ga.C[2])[((size_t)((b * NH + hh) * 64 + hd) << 11) + s2] = f2bf(v);
        } else if (mode == 3) {
          v += bias[col];
          ((float*)ga.C[3])[(size_t)row * 1024 + col] = v;
        } else {
          v += bias[col];
          int b = row >> 11, s2 = row & 2047, hh = col >> 6, hd = col & 63;
          ((uint16_t*)ga.C[mode])[(((size_t)(b * NH + hh) * 2048 + s2) << 6) + hd] = f2bf(v);
        }
      }
    }
  }
}

// Flash attention, K-split waves. WG=(head, 64-q tile, batch), 4 waves.
// Wave w owns k-rows [w*16, w*16+16) of each 64-k tile.
// S^T = K@Q^T (16x16x32); P goes directly from softmax registers into a
// zero-padded 16x16x32 PV B-operand (slots 0..3 = the S^T C-layout rows,
// slots 4..7 = 0; V A-frag replicates its 8B so padded products are 0).
// O^T/l partials merged across waves once at the end via LDS atomics.
// No online max: |score*cm*log2e/8| <= ~9 analytically; exp2 overflow-safe.
__global__ __launch_bounds__(256) void attn(const uint16_t* __restrict__ qp,
                                            const uint16_t* __restrict__ kp,
                                            const uint16_t* __restrict__ vt,
                                            const uint16_t* __restrict__ cm,
                                            uint16_t* __restrict__ ao) {
  int h = blockIdx.x, qt = blockIdx.y, b = blockIdx.z;
  int t = threadIdx.x;
  int lane = t & 63, w = t >> 6;
  int quad = lane >> 4, c = lane & 15;
  int sw = c & 7;

  __shared__ __align__(16) uint16_t pool[12288];  // 24KB
  uint16_t* Ks = pool;          // [k 64][hd 64], 16B chunks XOR-swizzled
  uint16_t* VTs = pool + 4096;  // [hd 64][k 64], swizzled
  uint16_t* CMs = pool + 8192;  // [q 64][k 64], swizzled
  float* Obuf = (float*)pool;               // reused: [hd 64][q, stride 66]
  float* lbuf = (float*)pool + 64 * 66;     // [q 64]

  size_t bh = (size_t)(b * NH + h);
  const uint16_t* Kb = kp + bh * (SEQ * 64);
  const uint16_t* Vb = vt + bh * (64 * SEQ);
  const uint16_t* CMb = cm + ((size_t)b * SEQ + qt * 64) * SEQ;

  // Q B-frags for all 4 q-groups, 2 hd-halves each (loaded once)
  bf16x8 qB[4][2];
  {
    const uint16_t* Qb = qp + bh * (SEQ * 64);
#pragma unroll
    for (int j = 0; j < 4; j++) {
      const uint16_t* qr = Qb + (size_t)(qt * 64 + j * 16 + c) * 64;
      qB[j][0] = *(const bf16x8*)(qr + quad * 8);
      qB[j][1] = *(const bf16x8*)(qr + 32 + quad * 8);
    }
  }

  f32x4 Oacc[4][4] = {};   // [hd-group i][q-group j]
  float l_part[4] = {};

  int srow = w * 8 + (lane >> 3);            // staging row (of 32)
  int sch = ((lane & 7) ^ (srow & 7)) * 8;   // global-side XOR chunk swizzle
  uint16_t* KsW = Ks + w * 512;
  uint16_t* VsW = VTs + w * 512;
  uint16_t* CsW = CMs + w * 512;

  // this wave's 8B k-slice (elements w*16+quad*4 .. +4), swizzle-adjusted
  int vchunk = ((2 * w + (quad >> 1)) ^ sw) * 8 + (quad & 1) * 4;

  for (int kt = 0; kt < SEQ; kt += 64) {
    __syncthreads();
    gload16(Kb + (size_t)(kt + srow) * 64 + sch, KsW);
    gload16(Kb + (size_t)(kt + 32 + srow) * 64 + sch, KsW + 2048);
    gload16(Vb + (size_t)srow * SEQ + kt + sch, VsW);
    gload16(Vb + (size_t)(32 + srow) * SEQ + kt + sch, VsW + 2048);
    gload16(CMb + (size_t)srow * SEQ + kt + sch, CsW);
    gload16(CMb + (size_t)(32 + srow) * SEQ + kt + sch, CsW + 2048);
    __syncthreads();

    // S^T for this wave's 16 k-rows x 64 q
    bf16x8 a0 = *(const bf16x8*)&Ks[(w * 16 + c) * 64 + ((quad ^ sw) * 8)];
    bf16x8 a1 = *(const bf16x8*)&Ks[(w * 16 + c) * 64 + (((4 + quad) ^ sw) * 8)];
    f32x4 st[4];
#pragma unroll
    for (int j = 0; j < 4; j++) {
      f32x4 z = {};
      z = MFMA32(a0, qB[j][0], z);
      st[j] = MFMA32(a1, qB[j][1], z);
    }

    // softmax (fixed max) + P into zero-padded PV B-frags
    bf16x8 pfr[4];
#pragma unroll
    for (int j = 0; j < 4; j++) {
      ushort4 cmv = *(const ushort4*)&CMs[(j * 16 + c) * 64 + vchunk];
      const uint16_t* cmp_ = (const uint16_t*)&cmv;
      float e[4];
#pragma unroll
      for (int r = 0; r < 4; r++) {
        float cf = bf2f(cmp_[r]);
        float sv = st[j][r] * cf;
        sv = (cf < 0.0f) ? NEG_BIG : sv;
        e[r] = EXP2F(sv);
        l_part[j] += e[r];
      }
      union { uint32_t u[4]; bf16x8 v; } pb;
      pb.u[0] = pack2bf_trunc(e[0], e[1]);
      pb.u[1] = pack2bf_trunc(e[2], e[3]);
      pb.u[2] = 0; pb.u[3] = 0;
      pfr[j] = pb.v;
    }

    // O^T partial += V^T(hd x k16) @ P^T(k16 x q); padded half contributes 0
#pragma unroll
    for (int i = 0; i < 4; i++) {
      uint2 vd = *(const uint2*)&VTs[(i * 16 + c) * 64 + vchunk];
      union { uint32_t u[4]; bf16x8 v; } vb;
      vb.u[0] = vd.x; vb.u[1] = vd.y; vb.u[2] = vd.x; vb.u[3] = vd.y;  // finite
#pragma unroll
      for (int j = 0; j < 4; j++)
        Oacc[i][j] = MFMA32(vb.v, pfr[j], Oacc[i][j]);
    }
  }

  // ---- cross-wave merge (once) ----
  __syncthreads();
  for (int z = t; z < 64 * 66 + 64; z += 256) ((float*)pool)[z] = 0.0f;
  __syncthreads();
#pragma unroll
  for (int j = 0; j < 4; j++) {
    atomicAdd(&lbuf[j * 16 + c], l_part[j]);
#pragma unroll
    for (int i = 0; i < 4; i++)
#pragma unroll
      for (int r = 0; r < 4; r++)
        atomicAdd(&Obuf[(i * 16 + quad * 4 + r) * 66 + j * 16 + c], Oacc[i][j][r]);
  }
  __syncthreads();

  // write: thread -> (q = t>>3 (+32), hd chunk part*8..+8), coalesced uint4
  int q0 = t >> 3, part = t & 7;
  uint16_t* aob0 = ao + ((size_t)(b * SEQ + qt * 64)) * HDIM + h * 64 + part * 8;
#pragma unroll
  for (int rnd = 0; rnd < 2; rnd++) {
    int qq = q0 + rnd * 32;
    float inv = 1.0f / lbuf[qq];
    float v[8];
#pragma unroll
    for (int e = 0; e < 8; e++) v[e] = Obuf[(part * 8 + e) * 66 + qq] * inv;
    uint4 pkv;
    pkv.x = pack2bf_rne(v[0], v[1]);
    pkv.y = pack2bf_rne(v[2], v[3]);
    pkv.z = pack2bf_rne(v[4], v[5]);
    pkv.w = pack2bf_rne(v[6], v[7]);
    *(uint4*)(aob0 + (size_t)qq * HDIM) = pkv;
  }
}

extern "C" void kernel_launch(void* const* d_in, const int* in_sizes, int n_in,
                              void* d_out, int out_size, void* d_ws, size_t ws_size,
                              hipStream_t stream) {
  (void)in_sizes; (void)n_in; (void)out_size; (void)ws_size;
  const float* query = (const float*)d_in[0];
  const float* key   = (const float*)d_in[1];
  const float* value = (const float*)d_in[2];
  const int*   mask  = (const int*)d_in[3];
  const float* smask = (const float*)d_in[4];
  const float* Wq = (const float*)d_in[5];
  const float* bq = (const float*)d_in[6];
  const float* Wk = (const float*)d_in[7];
  const float* bk = (const float*)d_in[8];
  const float* Wv = (const float*)d_in[9];
  const float* bv = (const float*)d_in[10];
  const float* Wo = (const float*)d_in[11];
  const float* bo = (const float*)d_in[12];

  char* p = (char*)d_ws;
  uint16_t* xq  = (uint16_t*)p; p += (size_t)2 * SEQ * HDIM * 2;
  uint16_t* xk  = (uint16_t*)p; p += (size_t)2 * SEQ * HDIM * 2;
  uint16_t* xv  = (uint16_t*)p; p += (size_t)2 * SEQ * HDIM * 2;
  uint16_t* wqb = (uint16_t*)p; p += (size_t)HDIM * HDIM * 2;
  uint16_t* wkb = (uint16_t*)p; p += (size_t)HDIM * HDIM * 2;
  uint16_t* wvb = (uint16_t*)p; p += (size_t)HDIM * HDIM * 2;
  uint16_t* wob = (uint16_t*)p; p += (size_t)HDIM * HDIM * 2;
  uint16_t* qp  = (uint16_t*)p; p += (size_t)2 * NH * SEQ * 64 * 2;
  uint16_t* kpp = (uint16_t*)p; p += (size_t)2 * NH * SEQ * 64 * 2;
  uint16_t* vtp = (uint16_t*)p; p += (size_t)2 * NH * SEQ * 64 * 2;
  uint16_t* cmw = (uint16_t*)p; p += (size_t)2 * SEQ * SEQ * 2;
  uint16_t* aob = (uint16_t*)p; p += (size_t)2 * SEQ * HDIM * 2;

  CvtArgs ca;
  ca.src[0] = query; ca.dst[0] = xq;
  ca.src[1] = key;   ca.dst[1] = xk;
  ca.src[2] = value; ca.dst[2] = xv;
  ca.src[3] = Wq;    ca.dst[3] = wqb;
  ca.src[4] = Wk;    ca.dst[4] = wkb;
  ca.src[5] = Wv;    ca.dst[5] = wvb;
  ca.src[6] = Wo;    ca.dst[6] = wob;
  cvt_bf16<<<8192, 256, 0, stream>>>(ca);

  cm_prep<<<4096, 256, 0, stream>>>((const int4*)mask, (const float4*)smask, (uint4*)cmw);

  GemmArgs ga;
  ga.A[0] = xq;  ga.B[0] = wqb; ga.bias[0] = bq; ga.C[0] = qp;
  ga.A[1] = xk;  ga.B[1] = wkb; ga.bias[1] = bk; ga.C[1] = kpp;
  ga.A[2] = wvb; ga.B[2] = xv;  ga.bias[2] = bv; ga.C[2] = vtp;
  ga.A[3] = aob; ga.B[3] = wob; ga.bias[3] = bo; ga.C[3] = d_out;

  gemm_bt<<<dim3(256, 3), 256, 0, stream>>>(ga, 0);
  attn<<<dim3(NH, SEQ / 64, 2), 256, 0, stream>>>(qp, kpp, vtp, cmw, aob);
  gemm_bt<<<dim3(256, 1), 256, 0, stream>>>(ga, 3);
}